// Round 10
// baseline (256.616 us; speedup 1.0000x reference)
//
#include <hip/hip_runtime.h>
#include <math.h>

#define HWDIM 256
#define CH 32
#define NB 8
#define TILE 16
#define NLOC (NB*HWDIM*HWDIM)   /* 524288 locations */
#define R_CLAMP 4.9517189f      /* artanh(0.9999) */
#define MAXN 0.9999f
#define BN_EPS 1e-5f
#define EPSF 1e-5f
#define NBLK 2048
#define OST 264                 /* out_kernel LDS row stride (floats) */

typedef __attribute__((ext_vector_type(8))) _Float16 half8;
typedef __attribute__((ext_vector_type(4))) _Float16 half4;
typedef __attribute__((ext_vector_type(4))) float floatx4;

__device__ __forceinline__ float artanh_fast(float n) {
    float t = fminf(n, 1.0f - 1e-5f);
    // artanh(t) = 0.5*ln((1+t)/(1-t)); one v_log + fast divide; ~1e-6 rel err << fp16 path
    return 0.5f * __logf(__fdividef(1.0f + t, 1.0f - t));
}

// pack both weight tensors to fp16: w[co][ci][3][3] -> wp[((o*4+g)*32+co)*8+j], ci=g*8+j
// Also zeroes gstat[128] (BN accumulators for both convs; workspace is poisoned each run).
__global__ __launch_bounds__(256) void wprep_kernel(
    const float* __restrict__ w1, const float* __restrict__ w2,
    _Float16* __restrict__ wp1, _Float16* __restrict__ wp2,
    float* __restrict__ gstat)
{
    int idx = blockIdx.x * 256 + threadIdx.x;
    if (blockIdx.x == 0 && threadIdx.x < 128) gstat[threadIdx.x] = 0.f;
    if (idx >= 2*CH*CH*9) return;
    int s = idx >= CH*CH*9;
    int id = idx - s*(CH*CH*9);
    const float* w = s ? w2 : w1;
    _Float16* wp = s ? wp2 : wp1;
    int j  = id & 7;
    int r  = id >> 3;
    int co = r & 31;
    int og = r >> 5;
    int g  = og & 3;
    int o  = og >> 2;
    int ci = g*8 + j;
    wp[id] = (_Float16)w[(co*CH + ci)*9 + o];
}

// STAGE 1: src = x fp32 NCHW, staging transform = logmap0
// STAGE 2: src = t1 fp16 channel-minor [N*H*W][32], transform = bn1+clampnorm+relu,
//          with bn1 scale/shift computed per-block from gstat_in (fence-free fused finalize).
// dst (both stages): fp16 channel-minor [N*H*W][32]
// BN stats out: per-block sums via plain device-scope atomicAdd into gstat_out[64]
// (NO fence, NO ticket — round-7's +80us came from per-block __threadfence, not atomics).
// Conv body = round-9 proven config (VGPR 48, no spill, 42-47 us).
template<int STAGE>
__global__ __launch_bounds__(256) void conv_mfma_kernel(
    const void* __restrict__ srcv,
    const _Float16* __restrict__ wp,      // [9][4][32co][8ci] fp16
    const float* __restrict__ bias,
    const float* __restrict__ gstat_in,   // [64] prev-conv BN sums (STAGE 2)
    const float* __restrict__ gamma, const float* __restrict__ beta, // (STAGE 2)
    _Float16* __restrict__ dst,
    float* __restrict__ gstat_out)        // [64] this conv's BN accumulator
{
    __shared__ _Float16 ah[10368];        // [18y][4g][18x][8ci] = 20736 B
    __shared__ float red[4][64];
    __shared__ float scshL[64];           // STAGE2: [0..31]=scale, [32..63]=shift

    const int tid = threadIdx.x;
    // XCD-aware swizzle: flat&7 -> image index, so each XCD rasters one image
    const int flat = blockIdx.x;
    const int bz = flat & 7;
    const int t  = flat >> 3;
    const int by = t >> 4, bx = t & 15;
    const int h0 = by*TILE - 1, w0 = bx*TILE - 1;

    if (STAGE == 2) {
        if (tid < 32) {
            float sum = gstat_in[tid];
            float sq  = gstat_in[32 + tid];
            const float NS = (float)NLOC;
            float mean = sum / NS;
            float var = fmaxf(sq / NS - mean*mean, 0.0f);
            float sc = gamma[tid] * __frsqrt_rn(var + BN_EPS);
            scshL[tid] = sc;
            scshL[32 + tid] = beta[tid] - mean*sc;
        }
        __syncthreads();
    }

    // ---- stage + transform -> fp16 A-tile in LDS (sequential per-loc loop) ----
    #pragma unroll 1
    for (int loc = tid; loc < 324; loc += 256) {
        int y = loc / 18, x = loc - y*18;
        int gh = h0 + y, gw = w0 + x;
        if (gh < 0 || gh >= HWDIM || gw < 0 || gw >= HWDIM) {
            half8 z = {0,0,0,0,0,0,0,0};
            #pragma unroll
            for (int g = 0; g < 4; g++) *(half8*)(ah + ((y*4+g)*18 + x)*8) = z;
            continue;
        }
        float v[CH]; float n2 = 0.f;
        if (STAGE == 1) {
            const float* p = (const float*)srcv + ((size_t)bz*CH << 16) + gh*HWDIM + gw;
            #pragma unroll
            for (int c = 0; c < CH; c++) { float t0 = p[(size_t)c << 16]; v[c] = t0; n2 = fmaf(t0, t0, n2); }
            float n = fmaxf(sqrtf(n2), EPSF);
            float f = __fdividef(artanh_fast(n), n);
            #pragma unroll
            for (int c = 0; c < CH; c++) v[c] *= f;
        } else {
            const _Float16* p = (const _Float16*)srcv + (((size_t)bz << 16) + gh*HWDIM + gw)*CH;
            half8 raw[4];
            #pragma unroll
            for (int k = 0; k < 4; k++) raw[k] = *(const half8*)(p + 8*k);
            #pragma unroll
            for (int c = 0; c < CH; c++) {
                float t0 = fmaf((float)raw[c>>3][c&7], scshL[c], scshL[CH + c]);
                v[c] = t0; n2 = fmaf(t0, t0, n2);
            }
            float n = sqrtf(n2);
            float f = (n > R_CLAMP) ? __fdividef(R_CLAMP, n) : 1.0f;
            #pragma unroll
            for (int c = 0; c < CH; c++) v[c] = fmaxf(v[c]*f, 0.0f);
        }
        #pragma unroll
        for (int g = 0; g < 4; g++) {
            half8 hv;
            #pragma unroll
            for (int j = 0; j < 8; j++) hv[j] = (_Float16)v[g*8 + j];
            *(half8*)(ah + ((y*4+g)*18 + x)*8) = hv;
        }
    }
    __syncthreads();

    const int lane = tid & 63, wave = tid >> 6;
    const int xx = lane & 15, q = lane >> 4;

    floatx4 acc[4][2];
    #pragma unroll
    for (int i = 0; i < 4; i++) {
        acc[i][0] = (floatx4){0.f,0.f,0.f,0.f};
        acc[i][1] = (floatx4){0.f,0.f,0.f,0.f};
    }

    // ---- implicit GEMM, swapped operands: A = weights (m=co), B = acts (n=loc) ----
    // D[m=co=q*4+r(+16h)][n=loc x=xx] per loc-tile i (y = wave*4+i)
    __builtin_amdgcn_s_setprio(1);
    #pragma unroll
    for (int dx = 0; dx < 3; dx++) {
        half8 af[6];
        #pragma unroll
        for (int yy = 0; yy < 6; yy++)
            af[yy] = *(const half8*)(ah + (((wave*4+yy)*4 + q)*18 + xx + dx)*8);
        #pragma unroll
        for (int dy = 0; dy < 3; dy++) {
            const int o = dy*3 + dx;
            const _Float16* wb = wp + (size_t)((o*4 + q)*32)*8;
            half8 wf0 = *(const half8*)(wb + xx*8);          // A[m=xx][k=q*8+j], co 0..15
            half8 wf1 = *(const half8*)(wb + (xx+16)*8);     // co 16..31
            #pragma unroll
            for (int i = 0; i < 4; i++) {
                acc[i][0] = __builtin_amdgcn_mfma_f32_16x16x32_f16(wf0, af[i+dy], acc[i][0], 0,0,0);
                acc[i][1] = __builtin_amdgcn_mfma_f32_16x16x32_f16(wf1, af[i+dy], acc[i][1], 0,0,0);
            }
        }
    }
    __builtin_amdgcn_s_setprio(0);

    // ---- register epilogue: thread owns ch {q*4+r, q*4+r+16} of loc (y=wave*4+i, x=xx) ----
    float bs[8];
    #pragma unroll
    for (int r = 0; r < 4; r++) { bs[r] = bias[q*4+r]; bs[4+r] = bias[q*4+r+16]; }
    float sv[8], qv[8];
    #pragma unroll
    for (int k = 0; k < 8; k++) { sv[k] = 0.f; qv[k] = 0.f; }

    _Float16* dp = dst + (((size_t)bz << 16) + (size_t)(by*TILE)*HWDIM + bx*TILE + xx)*CH + q*4;

    #pragma unroll
    for (int i = 0; i < 4; i++) {
        float n2 = 0.f;
        #pragma unroll
        for (int r = 0; r < 4; r++) {
            acc[i][0][r] += bs[r];
            acc[i][1][r] += bs[4+r];
            n2 = fmaf(acc[i][0][r], acc[i][0][r], n2);
            n2 = fmaf(acc[i][1][r], acc[i][1][r], n2);
        }
        n2 += __shfl_xor(n2, 16, 64);
        n2 += __shfl_xor(n2, 32, 64);
        float nn = sqrtf(n2);
        float f = (nn > R_CLAMP) ? __fdividef(R_CLAMP, nn) : 1.0f;
        half4 o0, o1;
        #pragma unroll
        for (int r = 0; r < 4; r++) {
            float a0 = acc[i][0][r] * f;
            float a1 = acc[i][1][r] * f;
            sv[r]   += a0; qv[r]   = fmaf(a0, a0, qv[r]);
            sv[4+r] += a1; qv[4+r] = fmaf(a1, a1, qv[4+r]);
            o0[r] = (_Float16)a0; o1[r] = (_Float16)a1;
        }
        _Float16* a = dp + (size_t)(wave*4 + i)*HWDIM*CH;
        *(half4*)(a)      = o0;
        *(half4*)(a + 16) = o1;
    }

    // quad-reduce BN partials over the 16 xx-lanes
    #pragma unroll
    for (int k = 0; k < 8; k++) {
        #pragma unroll
        for (int m = 1; m < 16; m <<= 1) {
            sv[k] += __shfl_xor(sv[k], m, 64);
            qv[k] += __shfl_xor(qv[k], m, 64);
        }
    }
    if (xx == 0) {
        #pragma unroll
        for (int r = 0; r < 4; r++) {
            red[wave][q*4+r]        = sv[r];
            red[wave][16 + q*4+r]   = sv[4+r];
            red[wave][32 + q*4+r]   = qv[r];
            red[wave][48 + q*4+r]   = qv[4+r];
        }
    }
    __syncthreads();
    if (tid < 64) {
        float s = red[0][tid] + red[1][tid] + red[2][tid] + red[3][tid];
        atomicAdd(&gstat_out[tid], s);    // device-scope by default; one 64-lane wave-atomic
    }
}

// read t4 fp16 channel-minor; bn2 (scale/shift from gstat, per-block) + clampnorm + relu
// + expmap0 + project; write fp32 NCHW
__global__ __launch_bounds__(256) void out_kernel(
    const _Float16* __restrict__ t4c,
    const float* __restrict__ gstat,      // [64] conv2 BN sums
    const float* __restrict__ gamma, const float* __restrict__ beta,
    float* __restrict__ out)
{
    __shared__ float outb[16*OST];
    __shared__ float scshL[64];
    const int w = threadIdx.x;
    const int h = blockIdx.x, n = blockIdx.y;

    if (w < 32) {
        float sum = gstat[w];
        float sq  = gstat[32 + w];
        const float NS = (float)NLOC;
        float mean = sum / NS;
        float var = fmaxf(sq / NS - mean*mean, 0.0f);
        float sc = gamma[w] * __frsqrt_rn(var + BN_EPS);
        scshL[w] = sc;
        scshL[32 + w] = beta[w] - mean*sc;
    }
    __syncthreads();

    const _Float16* p = t4c + (((size_t)n << 16) + (size_t)h*HWDIM + w)*CH;
    half8 raw[4];
    #pragma unroll
    for (int k = 0; k < 4; k++) raw[k] = *(const half8*)(p + 8*k);
    float u[CH]; float n2 = 0.f;
    #pragma unroll
    for (int c = 0; c < CH; c++) {
        float t = fmaf((float)raw[c>>3][c&7], scshL[c], scshL[CH+c]);
        u[c] = t; n2 = fmaf(t, t, n2);
    }
    float nn = sqrtf(n2);
    float f = (nn > R_CLAMP) ? __fdividef(R_CLAMP, nn) : 1.0f;
    float r2 = 0.f;
    #pragma unroll
    for (int c = 0; c < CH; c++) { float r = fmaxf(u[c]*f, 0.0f); u[c] = r; r2 = fmaf(r, r, r2); }
    float rn = fmaxf(sqrtf(r2), EPSF);
    // tanh(rn) = (e^{2rn}-1)/(e^{2rn}+1); rn <= ~4.95 so e^{2rn} <= ~2e4, safe in fp32
    float a = __expf(2.0f * rn);
    float th = __fdividef(a - 1.0f, a + 1.0f);
    float s = __fdividef(fminf(th, MAXN), rn);
    #pragma unroll
    for (int c = 0; c < CH; c++) u[c] *= s;

    #pragma unroll
    for (int hf = 0; hf < 2; hf++) {
        __syncthreads();
        #pragma unroll
        for (int c = 0; c < 16; c++) outb[c*OST + w] = u[hf*16 + c];
        __syncthreads();
        int co = threadIdx.x >> 4, seg = threadIdx.x & 15;
        const float* row = outb + co*OST + seg*16;
        float* gp = out + ((size_t)(n*CH + hf*16 + co) << 16) + (size_t)h*HWDIM + seg*16;
        #pragma unroll
        for (int k = 0; k < 4; k++) *(floatx4*)(gp + 4*k) = *(const floatx4*)(row + 4*k);
    }
}

extern "C" void kernel_launch(void* const* d_in, const int* in_sizes, int n_in,
                              void* d_out, int out_size, void* d_ws, size_t ws_size,
                              hipStream_t stream)
{
    const float* x   = (const float*)d_in[0];
    const float* w1  = (const float*)d_in[1];
    const float* b1  = (const float*)d_in[2];
    const float* g1  = (const float*)d_in[3];
    const float* be1 = (const float*)d_in[4];
    const float* w2  = (const float*)d_in[5];
    const float* b2  = (const float*)d_in[6];
    const float* g2  = (const float*)d_in[7];
    const float* be2 = (const float*)d_in[8];
    float* outf = (float*)d_out;

    char* ws = (char*)d_ws;
    _Float16* wp1   = (_Float16*)ws;                     // 9216 halves
    _Float16* wp2   = wp1 + 9216;                        // 9216 halves -> 36864 B
    float* gstatA   = (float*)(ws + 36864);              // 64 floats
    float* gstatB   = gstatA + 64;                       // 64 floats (contiguous: wprep zeroes 128)
    _Float16* t1c   = (_Float16*)(ws + 37632);           // 16.7M halves (32 MB), 16B-aligned
    _Float16* t4c   = t1c + (size_t)NLOC*CH;             // 16.7M halves (32 MB)

    wprep_kernel<<<72, 256, 0, stream>>>(w1, w2, wp1, wp2, gstatA);

    conv_mfma_kernel<1><<<NBLK, 256, 0, stream>>>(x,   wp1, b1, nullptr, nullptr, nullptr, t1c, gstatA);
    conv_mfma_kernel<2><<<NBLK, 256, 0, stream>>>(t1c, wp2, b2, gstatA, g1, be1,          t4c, gstatB);
    out_kernel<<<dim3(HWDIM, NB), 256, 0, stream>>>(t4c, gstatB, g2, be2, outf);
}

// Round 11
// 201.532 us; speedup vs baseline: 1.2733x; 1.2733x over previous
//
#include <hip/hip_runtime.h>
#include <math.h>

#define HWDIM 256
#define CH 32
#define NB 8
#define TILE 16
#define NLOC (NB*HWDIM*HWDIM)   /* 524288 locations */
#define R_CLAMP 4.9517189f      /* artanh(0.9999) */
#define MAXN 0.9999f
#define BN_EPS 1e-5f
#define EPSF 1e-5f
#define NBLK 2048               /* conv1 grid; also partials stride */
#define NBLK2 512               /* conv2 grid (4 tiles/block) */
#define OST 264                 /* out_kernel LDS row stride (floats) */

typedef __attribute__((ext_vector_type(8))) _Float16 half8;
typedef __attribute__((ext_vector_type(4))) _Float16 half4;
typedef __attribute__((ext_vector_type(4))) float floatx4;

__device__ __forceinline__ float artanh_fast(float n) {
    float t = fminf(n, 1.0f - 1e-5f);
    return 0.5f * __logf(__fdividef(1.0f + t, 1.0f - t));
}

// pack both weight tensors to fp16: w[co][ci][3][3] -> wp[((o*4+g)*32+co)*8+j], ci=g*8+j
__global__ __launch_bounds__(256) void wprep_kernel(
    const float* __restrict__ w1, const float* __restrict__ w2,
    _Float16* __restrict__ wp1, _Float16* __restrict__ wp2)
{
    int idx = blockIdx.x * 256 + threadIdx.x;
    if (idx >= 2*CH*CH*9) return;
    int s = idx >= CH*CH*9;
    int id = idx - s*(CH*CH*9);
    const float* w = s ? w2 : w1;
    _Float16* wp = s ? wp2 : wp1;
    int j  = id & 7;
    int r  = id >> 3;
    int co = r & 31;
    int og = r >> 5;
    int g  = og & 3;
    int o  = og >> 2;
    int ci = g*8 + j;
    wp[id] = (_Float16)w[(co*CH + ci)*9 + o];
}

// conv1: round-9 proven body (42-47 us, VGPR 48, clean traffic). src = x fp32 NCHW,
// staging transform = logmap0; dst fp16 channel-minor; partials via transposed array
// (rounds 7/10 lesson: fence/same-address atomics cost 25-80 us — array + tiny
// finalize dispatch is the cheap cross-block reduction on 8-XCD parts).
__global__ __launch_bounds__(256) void conv1_kernel(
    const float* __restrict__ src,
    const _Float16* __restrict__ wp,
    const float* __restrict__ bias,
    _Float16* __restrict__ dst,
    float* __restrict__ partials)         // [64][NBLK] transposed
{
    __shared__ _Float16 ah[10368];        // [18y][4g][18x][8ci] = 20736 B
    __shared__ float red[4][64];

    const int tid = threadIdx.x;
    const int flat = blockIdx.x;
    const int bz = flat & 7;
    const int t  = flat >> 3;
    const int by = t >> 4, bx = t & 15;
    const int h0 = by*TILE - 1, w0 = bx*TILE - 1;

    #pragma unroll 1
    for (int loc = tid; loc < 324; loc += 256) {
        int y = loc / 18, x = loc - y*18;
        int gh = h0 + y, gw = w0 + x;
        if (gh < 0 || gh >= HWDIM || gw < 0 || gw >= HWDIM) {
            half8 z = {0,0,0,0,0,0,0,0};
            #pragma unroll
            for (int g = 0; g < 4; g++) *(half8*)(ah + ((y*4+g)*18 + x)*8) = z;
            continue;
        }
        float v[CH]; float n2 = 0.f;
        const float* p = src + ((size_t)bz*CH << 16) + gh*HWDIM + gw;
        #pragma unroll
        for (int c = 0; c < CH; c++) { float t0 = p[(size_t)c << 16]; v[c] = t0; n2 = fmaf(t0, t0, n2); }
        float n = fmaxf(sqrtf(n2), EPSF);
        float f = __fdividef(artanh_fast(n), n);
        #pragma unroll
        for (int g = 0; g < 4; g++) {
            half8 hv;
            #pragma unroll
            for (int j = 0; j < 8; j++) hv[j] = (_Float16)(v[g*8 + j] * f);
            *(half8*)(ah + ((y*4+g)*18 + x)*8) = hv;
        }
    }
    __syncthreads();

    const int lane = tid & 63, wave = tid >> 6;
    const int xx = lane & 15, q = lane >> 4;

    floatx4 acc[4][2];
    #pragma unroll
    for (int i = 0; i < 4; i++) {
        acc[i][0] = (floatx4){0.f,0.f,0.f,0.f};
        acc[i][1] = (floatx4){0.f,0.f,0.f,0.f};
    }

    __builtin_amdgcn_s_setprio(1);
    #pragma unroll
    for (int dx = 0; dx < 3; dx++) {
        half8 af[6];
        #pragma unroll
        for (int yy = 0; yy < 6; yy++)
            af[yy] = *(const half8*)(ah + (((wave*4+yy)*4 + q)*18 + xx + dx)*8);
        #pragma unroll
        for (int dy = 0; dy < 3; dy++) {
            const int o = dy*3 + dx;
            const _Float16* wb = wp + (size_t)((o*4 + q)*32)*8;
            half8 wf0 = *(const half8*)(wb + xx*8);
            half8 wf1 = *(const half8*)(wb + (xx+16)*8);
            #pragma unroll
            for (int i = 0; i < 4; i++) {
                acc[i][0] = __builtin_amdgcn_mfma_f32_16x16x32_f16(wf0, af[i+dy], acc[i][0], 0,0,0);
                acc[i][1] = __builtin_amdgcn_mfma_f32_16x16x32_f16(wf1, af[i+dy], acc[i][1], 0,0,0);
            }
        }
    }
    __builtin_amdgcn_s_setprio(0);

    float bs[8];
    #pragma unroll
    for (int r = 0; r < 4; r++) { bs[r] = bias[q*4+r]; bs[4+r] = bias[q*4+r+16]; }
    float sv[8], qv[8];
    #pragma unroll
    for (int k = 0; k < 8; k++) { sv[k] = 0.f; qv[k] = 0.f; }

    _Float16* dp = dst + (((size_t)bz << 16) + (size_t)(by*TILE)*HWDIM + bx*TILE + xx)*CH + q*4;

    #pragma unroll
    for (int i = 0; i < 4; i++) {
        float n2 = 0.f;
        #pragma unroll
        for (int r = 0; r < 4; r++) {
            acc[i][0][r] += bs[r];
            acc[i][1][r] += bs[4+r];
            n2 = fmaf(acc[i][0][r], acc[i][0][r], n2);
            n2 = fmaf(acc[i][1][r], acc[i][1][r], n2);
        }
        n2 += __shfl_xor(n2, 16, 64);
        n2 += __shfl_xor(n2, 32, 64);
        float nn = sqrtf(n2);
        float f = (nn > R_CLAMP) ? __fdividef(R_CLAMP, nn) : 1.0f;
        half4 o0, o1;
        #pragma unroll
        for (int r = 0; r < 4; r++) {
            float a0 = acc[i][0][r] * f;
            float a1 = acc[i][1][r] * f;
            sv[r]   += a0; qv[r]   = fmaf(a0, a0, qv[r]);
            sv[4+r] += a1; qv[4+r] = fmaf(a1, a1, qv[4+r]);
            o0[r] = (_Float16)a0; o1[r] = (_Float16)a1;
        }
        _Float16* a = dp + (size_t)(wave*4 + i)*HWDIM*CH;
        *(half4*)(a)      = o0;
        *(half4*)(a + 16) = o1;
    }

    #pragma unroll
    for (int k = 0; k < 8; k++) {
        #pragma unroll
        for (int m = 1; m < 16; m <<= 1) {
            sv[k] += __shfl_xor(sv[k], m, 64);
            qv[k] += __shfl_xor(qv[k], m, 64);
        }
    }
    if (xx == 0) {
        #pragma unroll
        for (int r = 0; r < 4; r++) {
            red[wave][q*4+r]        = sv[r];
            red[wave][16 + q*4+r]   = sv[4+r];
            red[wave][32 + q*4+r]   = qv[r];
            red[wave][48 + q*4+r]   = qv[4+r];
        }
    }
    __syncthreads();
    if (tid < 64) {
        float s = red[0][tid] + red[1][tid] + red[2][tid] + red[3][tid];
        partials[(size_t)tid*NBLK + flat] = s;
    }
}

// conv2: DMA-pipelined (T3/T4). 512 blocks x 4 tiles marching in x.
// LDS A[2] double buffer filled by global_load_lds (zero-VGPR staging); weights in LDS
// so the MFMA phase issues NO VMEM (in-flight DMAs never force-drain); counted
// s_waitcnt vmcnt(5) keeps next tile's 5 DMAs/wave flying across raw s_barriers.
// bn1+clamp+relu applied as in-place LDS fixup pass (also zeroes halo pad slots).
__global__ __launch_bounds__(256) void conv2_dma_kernel(
    const _Float16* __restrict__ src,     // t1 fp16 channel-minor
    const _Float16* __restrict__ wp,      // [9][4][32co][8ci] fp16
    const float* __restrict__ bias,
    const float* __restrict__ scsh,       // [2*CH] bn1 scale/shift
    _Float16* __restrict__ dst,
    float* __restrict__ partials)         // [64][NBLK] transposed, b < NBLK2
{
    __shared__ _Float16 wlds[9216];       // 18432 B
    __shared__ _Float16 A[2][10368];      // 2 x 20736 B
    __shared__ float red[4][64];          // total 60928 B -> 2 blocks/CU

    const int tid = threadIdx.x;
    const int b   = blockIdx.x;           // 0..511
    const int bz  = b & 7;
    const int tb  = b >> 3;               // 0..63
    const int by  = tb >> 2;              // 0..15
    const int bx0 = (tb & 3) * 4;         // 0,4,8,12
    const int h0  = by*TILE - 1;

    const int lane = tid & 63, wave = tid >> 6;
    const int xx = lane & 15, q = lane >> 4;

    // weights -> LDS (compiler inserts the vmcnt waits at the ds_writes; all retired
    // before the first DMA's counted wait matters)
    for (int i = tid; i < 1152; i += 256)
        *(half8*)(wlds + (size_t)i*8) = *(const half8*)(wp + (size_t)i*8);

    // Staging for tile jj into buffer bb. Item it=(y*4+g)*18+x (16B = ch group g of
    // halo loc (y,x)); DMA instr m=k*4+wave covers items m*64+lane at LDS A[bb]+it*16B.
    // Leftover items 1280..1295 (y=17,g=3,x=2..17) via 16 threads' reg load (issued
    // BEFORE the DMAs so its ds_write's implicit wait is vmcnt(5), keeping DMAs in flight).
    // OOB addresses clamped (garbage lands in pad slots; fixup pass zeroes them).
    #define STAGE_ISSUE(jj, bb) do {                                                       \
        const int w0_ = (bx0 + (jj))*TILE - 1;                                             \
        half8 lreg_ = {0,0,0,0,0,0,0,0};                                                   \
        if (tid < 16) {                                                                    \
            int gh_ = h0 + 17, gw_ = w0_ + 2 + tid;                                        \
            int ghc_ = gh_ < 0 ? 0 : (gh_ > 255 ? 255 : gh_);                              \
            int gwc_ = gw_ < 0 ? 0 : (gw_ > 255 ? 255 : gw_);                              \
            lreg_ = *(const half8*)(src + (((size_t)bz << 16) + ghc_*HWDIM + gwc_)*CH + 24); \
        }                                                                                  \
        _Pragma("unroll")                                                                  \
        for (int k_ = 0; k_ < 5; k_++) {                                                   \
            int it_ = (k_*4 + wave)*64 + lane;                                             \
            int y_ = it_ / 72; int rm_ = it_ - y_*72;                                      \
            int g_ = rm_ / 18; int x_ = rm_ - g_*18;                                       \
            int gh_ = h0 + y_, gw_ = w0_ + x_;                                             \
            int ghc_ = gh_ < 0 ? 0 : (gh_ > 255 ? 255 : gh_);                              \
            int gwc_ = gw_ < 0 ? 0 : (gw_ > 255 ? 255 : gw_);                              \
            const _Float16* gp_ = src + (((size_t)bz << 16) + ghc_*HWDIM + gwc_)*CH + g_*8; \
            __builtin_amdgcn_global_load_lds(                                              \
                (const __attribute__((address_space(1))) void*)gp_,                        \
                (__attribute__((address_space(3))) void*)(&A[bb][0] + (size_t)((k_*4 + wave)*64)*8), \
                16, 0, 0);                                                                 \
        }                                                                                  \
        if (tid < 16) *(half8*)(&A[bb][(size_t)(1280 + tid)*8]) = lreg_;                   \
    } while (0)

    float bs[8];
    #pragma unroll
    for (int r = 0; r < 4; r++) { bs[r] = bias[q*4+r]; bs[4+r] = bias[q*4+r+16]; }
    float sv[8], qv[8];
    #pragma unroll
    for (int k = 0; k < 8; k++) { sv[k] = 0.f; qv[k] = 0.f; }

    STAGE_ISSUE(0, 0);

    #pragma unroll 1
    for (int j = 0; j < 4; j++) {
        const int cur = j & 1;
        if (j + 1 < 4) {
            STAGE_ISSUE(j + 1, cur ^ 1);
            asm volatile("s_waitcnt vmcnt(5)" ::: "memory");   // tile-j DMAs retired; j+1's fly
        } else {
            asm volatile("s_waitcnt vmcnt(0)" ::: "memory");
        }
        asm volatile("s_waitcnt lgkmcnt(0)" ::: "memory");
        __builtin_amdgcn_s_barrier();                          // A[cur] fully populated
        __builtin_amdgcn_sched_barrier(0);

        // ---- in-place fixup + bn1+clamp+relu transform of A[cur] (sequential, 2 locs max) ----
        const int w0 = (bx0 + j)*TILE - 1;
        #pragma unroll 1
        for (int loc = tid; loc < 324; loc += 256) {
            int y = loc / 18, x = loc - y*18;
            int gh = h0 + y, gw = w0 + x;
            _Float16* b0 = &A[cur][(size_t)((y*4)*18 + x)*8];
            if (gh < 0 || gh >= HWDIM || gw < 0 || gw >= HWDIM) {
                half8 z = {0,0,0,0,0,0,0,0};
                #pragma unroll
                for (int g = 0; g < 4; g++) *(half8*)(b0 + g*144) = z;
                continue;
            }
            half8 raw[4];
            #pragma unroll
            for (int g = 0; g < 4; g++) raw[g] = *(const half8*)(b0 + g*144);
            float v[CH]; float n2 = 0.f;
            #pragma unroll
            for (int c = 0; c < CH; c++) {
                float t0 = fmaf((float)raw[c>>3][c&7], scsh[c], scsh[CH + c]);
                v[c] = t0; n2 = fmaf(t0, t0, n2);
            }
            float n = sqrtf(n2);
            float f = (n > R_CLAMP) ? __fdividef(R_CLAMP, n) : 1.0f;
            #pragma unroll
            for (int g = 0; g < 4; g++) {
                half8 hv;
                #pragma unroll
                for (int jj = 0; jj < 8; jj++) hv[jj] = (_Float16)fmaxf(v[g*8 + jj]*f, 0.0f);
                *(half8*)(b0 + g*144) = hv;
            }
        }
        asm volatile("s_waitcnt lgkmcnt(0)" ::: "memory");
        __builtin_amdgcn_s_barrier();
        __builtin_amdgcn_sched_barrier(0);

        // ---- MFMA (LDS-only operands: A[cur] + wlds) ----
        floatx4 acc[4][2];
        #pragma unroll
        for (int i = 0; i < 4; i++) {
            acc[i][0] = (floatx4){0.f,0.f,0.f,0.f};
            acc[i][1] = (floatx4){0.f,0.f,0.f,0.f};
        }
        __builtin_amdgcn_s_setprio(1);
        #pragma unroll
        for (int dx = 0; dx < 3; dx++) {
            half8 af[6];
            #pragma unroll
            for (int yy = 0; yy < 6; yy++)
                af[yy] = *(const half8*)(&A[cur][(size_t)(((wave*4+yy)*4 + q)*18 + xx + dx)*8]);
            #pragma unroll
            for (int dy = 0; dy < 3; dy++) {
                const int o = dy*3 + dx;
                const _Float16* wb = wlds + (size_t)((o*4 + q)*32)*8;
                half8 wf0 = *(const half8*)(wb + xx*8);
                half8 wf1 = *(const half8*)(wb + (xx+16)*8);
                #pragma unroll
                for (int i = 0; i < 4; i++) {
                    acc[i][0] = __builtin_amdgcn_mfma_f32_16x16x32_f16(wf0, af[i+dy], acc[i][0], 0,0,0);
                    acc[i][1] = __builtin_amdgcn_mfma_f32_16x16x32_f16(wf1, af[i+dy], acc[i][1], 0,0,0);
                }
            }
        }
        __builtin_amdgcn_s_setprio(0);

        // ---- epilogue (global stores enter vmcnt queue ahead of next DMAs; the next
        //      counted wait drains them first — correct, and they retire under the fixup) ----
        _Float16* dp = dst + (((size_t)bz << 16) + (size_t)(by*TILE)*HWDIM + (bx0 + j)*TILE + xx)*CH + q*4;
        #pragma unroll
        for (int i = 0; i < 4; i++) {
            float n2 = 0.f;
            #pragma unroll
            for (int r = 0; r < 4; r++) {
                acc[i][0][r] += bs[r];
                acc[i][1][r] += bs[4+r];
                n2 = fmaf(acc[i][0][r], acc[i][0][r], n2);
                n2 = fmaf(acc[i][1][r], acc[i][1][r], n2);
            }
            n2 += __shfl_xor(n2, 16, 64);
            n2 += __shfl_xor(n2, 32, 64);
            float nn = sqrtf(n2);
            float f = (nn > R_CLAMP) ? __fdividef(R_CLAMP, nn) : 1.0f;
            half4 o0, o1;
            #pragma unroll
            for (int r = 0; r < 4; r++) {
                float a0 = acc[i][0][r] * f;
                float a1 = acc[i][1][r] * f;
                sv[r]   += a0; qv[r]   = fmaf(a0, a0, qv[r]);
                sv[4+r] += a1; qv[4+r] = fmaf(a1, a1, qv[4+r]);
                o0[r] = (_Float16)a0; o1[r] = (_Float16)a1;
            }
            _Float16* a = dp + (size_t)(wave*4 + i)*HWDIM*CH;
            *(half4*)(a)      = o0;
            *(half4*)(a + 16) = o1;
        }
        asm volatile("s_waitcnt lgkmcnt(0)" ::: "memory");
        __builtin_amdgcn_s_barrier();      // all waves done reading A[cur] before its re-stage
        __builtin_amdgcn_sched_barrier(0);
    }
    #undef STAGE_ISSUE

    // BN partials accumulated over 4 tiles, one transposed-array write per block
    #pragma unroll
    for (int k = 0; k < 8; k++) {
        #pragma unroll
        for (int m = 1; m < 16; m <<= 1) {
            sv[k] += __shfl_xor(sv[k], m, 64);
            qv[k] += __shfl_xor(qv[k], m, 64);
        }
    }
    if (xx == 0) {
        #pragma unroll
        for (int r = 0; r < 4; r++) {
            red[wave][q*4+r]        = sv[r];
            red[wave][16 + q*4+r]   = sv[4+r];
            red[wave][32 + q*4+r]   = qv[r];
            red[wave][48 + q*4+r]   = qv[4+r];
        }
    }
    __syncthreads();
    if (tid < 64) {
        float s = red[0][tid] + red[1][tid] + red[2][tid] + red[3][tid];
        partials[(size_t)tid*NBLK + b] = s;
    }
}

__global__ __launch_bounds__(256) void finalize_kernel(
    const float* __restrict__ partials, int nblk,
    const float* __restrict__ g, const float* __restrict__ beta,
    float* __restrict__ scsh)
{
    __shared__ float ss[256], sq[256];
    const int c = blockIdx.x;
    const int tid = threadIdx.x;
    float s = 0.f, q = 0.f;
    for (int b = tid; b < nblk; b += 256) {
        s += partials[(size_t)c*NBLK + b];
        q += partials[(size_t)(CH + c)*NBLK + b];
    }
    ss[tid] = s; sq[tid] = q;
    __syncthreads();
    for (int st = 128; st > 0; st >>= 1) {
        if (tid < st) { ss[tid] += ss[tid+st]; sq[tid] += sq[tid+st]; }
        __syncthreads();
    }
    if (tid == 0) {
        const float NS = (float)NLOC;
        float mean = ss[0] / NS;
        float var = fmaxf(sq[0] / NS - mean*mean, 0.0f);
        float sc = g[c] / sqrtf(var + BN_EPS);
        scsh[c] = sc;
        scsh[CH + c] = beta[c] - mean*sc;
    }
}

// read t4 fp16 channel-minor; bn2+clampnorm+relu+expmap0+project; write fp32 NCHW
__global__ __launch_bounds__(256) void out_kernel(
    const _Float16* __restrict__ t4c, const float* __restrict__ scsh,
    float* __restrict__ out)
{
    __shared__ float outb[16*OST];
    const int w = threadIdx.x;
    const int h = blockIdx.x, n = blockIdx.y;
    const _Float16* p = t4c + (((size_t)n << 16) + (size_t)h*HWDIM + w)*CH;
    half8 raw[4];
    #pragma unroll
    for (int k = 0; k < 4; k++) raw[k] = *(const half8*)(p + 8*k);
    float u[CH]; float n2 = 0.f;
    #pragma unroll
    for (int c = 0; c < CH; c++) {
        float t = fmaf((float)raw[c>>3][c&7], scsh[c], scsh[CH+c]);
        u[c] = t; n2 = fmaf(t, t, n2);
    }
    float nn = sqrtf(n2);
    float f = (nn > R_CLAMP) ? __fdividef(R_CLAMP, nn) : 1.0f;
    float r2 = 0.f;
    #pragma unroll
    for (int c = 0; c < CH; c++) { float r = fmaxf(u[c]*f, 0.0f); u[c] = r; r2 = fmaf(r, r, r2); }
    float rn = fmaxf(sqrtf(r2), EPSF);
    float a = __expf(2.0f * rn);
    float th = __fdividef(a - 1.0f, a + 1.0f);
    float s = __fdividef(fminf(th, MAXN), rn);
    #pragma unroll
    for (int c = 0; c < CH; c++) u[c] *= s;

    #pragma unroll
    for (int hf = 0; hf < 2; hf++) {
        if (hf) __syncthreads();
        #pragma unroll
        for (int c = 0; c < 16; c++) outb[c*OST + w] = u[hf*16 + c];
        __syncthreads();
        int co = threadIdx.x >> 4, seg = threadIdx.x & 15;
        const float* row = outb + co*OST + seg*16;
        float* gp = out + ((size_t)(n*CH + hf*16 + co) << 16) + (size_t)h*HWDIM + seg*16;
        #pragma unroll
        for (int k = 0; k < 4; k++) *(floatx4*)(gp + 4*k) = *(const floatx4*)(row + 4*k);
    }
}

extern "C" void kernel_launch(void* const* d_in, const int* in_sizes, int n_in,
                              void* d_out, int out_size, void* d_ws, size_t ws_size,
                              hipStream_t stream)
{
    const float* x   = (const float*)d_in[0];
    const float* w1  = (const float*)d_in[1];
    const float* b1  = (const float*)d_in[2];
    const float* g1  = (const float*)d_in[3];
    const float* be1 = (const float*)d_in[4];
    const float* w2  = (const float*)d_in[5];
    const float* b2  = (const float*)d_in[6];
    const float* g2  = (const float*)d_in[7];
    const float* be2 = (const float*)d_in[8];
    float* outf = (float*)d_out;

    char* ws = (char*)d_ws;
    _Float16* wp1   = (_Float16*)ws;                     // 9216 halves
    _Float16* wp2   = wp1 + 9216;                        // 9216 halves -> 36864 B
    float* partials = (float*)(ws + 36864);              // [64][2048] floats
    float* scsh1    = (float*)(ws + 36864 + 524288);     // 64
    float* scsh2    = scsh1 + 64;                        // 64
    _Float16* t1c   = (_Float16*)(scsh2 + 64);           // 16.7M halves (32 MB)
    _Float16* t4c   = t1c + (size_t)NLOC*CH;             // 16.7M halves (32 MB)

    wprep_kernel<<<72, 256, 0, stream>>>(w1, w2, wp1, wp2);

    conv1_kernel<<<NBLK, 256, 0, stream>>>(x, wp1, b1, t1c, partials);
    finalize_kernel<<<32, 256, 0, stream>>>(partials, NBLK, g1, be1, scsh1);
    conv2_dma_kernel<<<NBLK2, 256, 0, stream>>>(t1c, wp2, b2, scsh1, t4c, partials);
    finalize_kernel<<<32, 256, 0, stream>>>(partials, NBLK2, g2, be2, scsh2);
    out_kernel<<<dim3(HWDIM, NB), 256, 0, stream>>>(t4c, scsh2, outf);
}